// Round 11
// baseline (190.376 us; speedup 1.0000x reference)
//
#include <hip/hip_runtime.h>

#define HID 128
#define NIN 21
#define EIN 2
#define NCLS 4

// ---------------- Global (d_ws) weight table, per hidden-dim d ----------------
// Units: u32 words. Row stride 68 u32 = 272 B. Rows 0..127, then a 25-word tail.
//  [0..10]   gi weight pairs (f16x2), scaled by L2E
//  [11..21]  gg weight pairs, scaled by 2*L2E
//  [22..32]  go weight pairs, scaled by L2E
//  [33..53]  nmpn pairs k=0..20: (L2E*W_nmpn[k][d], L2E*W_nmpn[k][128+d])
//  [54..56]  edge gate pairs (i,g,o)
//  [57..59]  f32 node biases bi, bg, bo (scaled)
//  [60..62]  f32 edge biases (scaled)
//  [63..66]  f32 W_fc[c][d]
//  [67]      pad
// Tail at word 128*68 = 8704: [0..20] f32 L2E*b_nmpn[k]; [21..24] f32 b_fc[c].
//
// KEY POINT (round 11): all row indices are wave-uniform (loop counter d), so
// these loads compile to s_load on the SCALAR pipe with SGPR destinations.
// v_dot2_f32_f16 (VOP3P) takes 1 SGPR operand directly. This removes ~3.7k
// ds_read_b128 per wave from the per-CU LDS pipe — the saturated resource
// identified by rounds 8-10 (TLP/ILP-invariant wall, VALUBusy*dur ~ 118us).
#define WSTRIDE 68
#define TAIL_OFF (HID * WSTRIDE)

#define L2E   1.4426950408889634f   // log2(e)
#define L2E2  2.8853900817779268f   // 2*log2(e)

typedef _Float16 h2_t __attribute__((ext_vector_type(2)));

__device__ __forceinline__ unsigned pack_f16(float a, float b) {
    h2_t h;
    h.x = (_Float16)a;
    h.y = (_Float16)b;
    return __builtin_bit_cast(unsigned, h);
}

__device__ __forceinline__ float fdot2_(unsigned a, unsigned b, float c) {
#if __has_builtin(__builtin_amdgcn_fdot2)
    return __builtin_amdgcn_fdot2(__builtin_bit_cast(h2_t, a),
                                  __builtin_bit_cast(h2_t, b), c, false);
#else
    h2_t ha = __builtin_bit_cast(h2_t, a), hb = __builtin_bit_cast(h2_t, b);
    return fmaf((float)ha.x, (float)hb.x, fmaf((float)ha.y, (float)hb.y, c));
#endif
}

__device__ __forceinline__ float rcp_(float x)  { return __builtin_amdgcn_rcpf(x); }
__device__ __forceinline__ float exp2_(float x) { return __builtin_amdgcn_exp2f(x); }
__device__ __forceinline__ float sigmoid_pre(float gp) { return rcp_(1.0f + exp2_(-gp)); }
__device__ __forceinline__ float tanh_pre(float gp) { return fmaf(2.0f, rcp_(1.0f + exp2_(-gp)), -1.0f); }
__device__ __forceinline__ float tanh_(float x) { return fmaf(2.0f, rcp_(1.0f + exp2_(-L2E2 * x)), -1.0f); }

// ---------------- kernel 1: pack the weight table into d_ws ----------------
__global__ __launch_bounds__(256)
void pack_weights(const float* __restrict__ W_ih_n,
                  const float* __restrict__ b_ih_n,
                  const float* __restrict__ b_hh_n,
                  const float* __restrict__ W_ih_e,
                  const float* __restrict__ b_ih_e,
                  const float* __restrict__ b_hh_e,
                  const float* __restrict__ W_nmpn,
                  const float* __restrict__ b_nmpn,
                  const float* __restrict__ W_fc,
                  const float* __restrict__ b_fc,
                  unsigned* __restrict__ wtab)
{
    const int tid = threadIdx.x;
    if (tid < HID) {
        const int d = tid;
        unsigned* row = &wtab[d * WSTRIDE];
        const float* wi = &W_ih_n[(0 * HID + d) * NIN];
        const float* wg = &W_ih_n[(2 * HID + d) * NIN];
        const float* wo = &W_ih_n[(3 * HID + d) * NIN];
#pragma unroll
        for (int j = 0; j < 10; ++j) {
            row[j]      = pack_f16(L2E  * wi[2 * j], L2E  * wi[2 * j + 1]);
            row[11 + j] = pack_f16(L2E2 * wg[2 * j], L2E2 * wg[2 * j + 1]);
            row[22 + j] = pack_f16(L2E  * wo[2 * j], L2E  * wo[2 * j + 1]);
        }
        row[10] = pack_f16(L2E  * wi[20], 0.0f);
        row[21] = pack_f16(L2E2 * wg[20], 0.0f);
        row[32] = pack_f16(L2E  * wo[20], 0.0f);
        row[57] = __float_as_uint(L2E  * (b_ih_n[0 * HID + d] + b_hh_n[0 * HID + d]));
        row[58] = __float_as_uint(L2E2 * (b_ih_n[2 * HID + d] + b_hh_n[2 * HID + d]));
        row[59] = __float_as_uint(L2E  * (b_ih_n[3 * HID + d] + b_hh_n[3 * HID + d]));
        row[67] = 0u;
    } else {
        const int d = tid - HID;
        unsigned* row = &wtab[d * WSTRIDE];
#pragma unroll
        for (int k = 0; k < NIN; ++k) {
            row[33 + k] = pack_f16(L2E * W_nmpn[k * 2 * HID + d],
                                   L2E * W_nmpn[k * 2 * HID + HID + d]);
        }
        row[54] = pack_f16(L2E  * W_ih_e[(0 * HID + d) * EIN + 0],
                           L2E  * W_ih_e[(0 * HID + d) * EIN + 1]);
        row[55] = pack_f16(L2E2 * W_ih_e[(2 * HID + d) * EIN + 0],
                           L2E2 * W_ih_e[(2 * HID + d) * EIN + 1]);
        row[56] = pack_f16(L2E  * W_ih_e[(3 * HID + d) * EIN + 0],
                           L2E  * W_ih_e[(3 * HID + d) * EIN + 1]);
        row[60] = __float_as_uint(L2E  * (b_ih_e[0 * HID + d] + b_hh_e[0 * HID + d]));
        row[61] = __float_as_uint(L2E2 * (b_ih_e[2 * HID + d] + b_hh_e[2 * HID + d]));
        row[62] = __float_as_uint(L2E  * (b_ih_e[3 * HID + d] + b_hh_e[3 * HID + d]));
#pragma unroll
        for (int c = 0; c < NCLS; ++c) row[63 + c] = __float_as_uint(W_fc[c * HID + d]);
    }
    if (tid < NIN) wtab[TAIL_OFF + tid] = __float_as_uint(L2E * b_nmpn[tid]);
    if (tid >= 32 && tid < 32 + NCLS) wtab[TAIL_OFF + 21 + (tid - 32)] = __float_as_uint(b_fc[tid - 32]);
}

// ---------------- kernel 2: fused GNN, weights via scalar loads ----------------
// (256,2): proven no-spill config (round 8: VGPR 68, WRITE_SIZE clean).
__global__ __launch_bounds__(256, 2)
void fused_gnn_kernel(const float* __restrict__ node_feat,  // N*21
                      const float* __restrict__ edge_feat,  // N*2
                      const unsigned* __restrict__ wtab,    // packed table in d_ws
                      float* __restrict__ out,              // N*4
                      int N)
{
    const int tid = threadIdx.x;
    const int n = blockIdx.x * blockDim.x + tid;
    const int nidx = (n < N) ? n : (N - 1);

    unsigned xnp[11];   // node input as f16 pairs
#pragma unroll
    for (int j = 0; j < 10; ++j)
        xnp[j] = pack_f16(node_feat[nidx * NIN + 2 * j], node_feat[nidx * NIN + 2 * j + 1]);
    xnp[10] = pack_f16(node_feat[nidx * NIN + 20], 0.0f);
    const unsigned xep = pack_f16(edge_feat[nidx * EIN + 0], edge_feat[nidx * EIN + 1]);

    float acc[NIN];   // L2E * xn1 pre-activation
#pragma unroll
    for (int k = 0; k < NIN; ++k) acc[k] = __uint_as_float(wtab[TAIL_OFF + k]);
    float lg[NCLS];
#pragma unroll
    for (int k = 0; k < NCLS; ++k) lg[k] = __uint_as_float(wtab[TAIL_OFF + 21 + k]);

    // ================= iteration 1 =================
    for (int d = 0; d < HID; ++d) {
        const unsigned* row = &wtab[d * WSTRIDE];   // uniform -> s_load / SGPRs

        float gi = __uint_as_float(row[57]);
        float gg = __uint_as_float(row[58]);
        float go = __uint_as_float(row[59]);
#pragma unroll
        for (int j = 0; j < 11; ++j) {
            gi = fdot2_(xnp[j], row[j],      gi);
            gg = fdot2_(xnp[j], row[11 + j], gg);
            go = fdot2_(xnp[j], row[22 + j], go);
        }
        const float cn = sigmoid_pre(gi) * tanh_pre(gg);
        const float hn = sigmoid_pre(go) * tanh_(cn);

        const float ei = fdot2_(xep, row[54], __uint_as_float(row[60]));
        const float eg = fdot2_(xep, row[55], __uint_as_float(row[61]));
        const float eo = fdot2_(xep, row[56], __uint_as_float(row[62]));
        const float ce = sigmoid_pre(ei) * tanh_pre(eg);
        const float he = sigmoid_pre(eo) * tanh_(ce);

        const unsigned hp = pack_f16(he, hn);
#pragma unroll
        for (int k = 0; k < NIN; ++k) acc[k] = fdot2_(hp, row[33 + k], acc[k]);
    }

    // xn1 = sigmoid(pre) -> repack as f16 pairs
#pragma unroll
    for (int j = 0; j < 10; ++j)
        xnp[j] = pack_f16(sigmoid_pre(acc[2 * j]), sigmoid_pre(acc[2 * j + 1]));
    xnp[10] = pack_f16(sigmoid_pre(acc[20]), 0.0f);

    // ================= iteration 2 (only h_n matters) =================
    for (int d = 0; d < HID; ++d) {
        const unsigned* row = &wtab[d * WSTRIDE];

        float gi = __uint_as_float(row[57]);
        float gg = __uint_as_float(row[58]);
        float go = __uint_as_float(row[59]);
#pragma unroll
        for (int j = 0; j < 11; ++j) {
            gi = fdot2_(xnp[j], row[j],      gi);
            gg = fdot2_(xnp[j], row[11 + j], gg);
            go = fdot2_(xnp[j], row[22 + j], go);
        }
        const float cn = sigmoid_pre(gi) * tanh_pre(gg);
        const float hn = sigmoid_pre(go) * tanh_(cn);

        lg[0] = fmaf(hn, __uint_as_float(row[63]), lg[0]);
        lg[1] = fmaf(hn, __uint_as_float(row[64]), lg[1]);
        lg[2] = fmaf(hn, __uint_as_float(row[65]), lg[2]);
        lg[3] = fmaf(hn, __uint_as_float(row[66]), lg[3]);
    }

    // ================= log_softmax over 4 classes + store =================
    const float m = fmaxf(fmaxf(lg[0], lg[1]), fmaxf(lg[2], lg[3]));
    float s = 0.0f;
#pragma unroll
    for (int k = 0; k < NCLS; ++k) s += exp2_(L2E * (lg[k] - m));
    const float lse = __logf(s) + m;

    if (n < N) {
        float4 o4;
        o4.x = lg[0] - lse;
        o4.y = lg[1] - lse;
        o4.z = lg[2] - lse;
        o4.w = lg[3] - lse;
        *reinterpret_cast<float4*>(&out[n * NCLS]) = o4;
    }
}

extern "C" void kernel_launch(void* const* d_in, const int* in_sizes, int n_in,
                              void* d_out, int out_size, void* d_ws, size_t ws_size,
                              hipStream_t stream)
{
    // setup_inputs order:
    // 0 node_feat, 1 edge_feat, 2 src, 3 dst, 4 W_ih_n, 5 W_hh_n, 6 b_ih_n,
    // 7 b_hh_n, 8 W_ih_e, 9 W_hh_e, 10 b_ih_e, 11 b_hh_e, 12 W_nmpn,
    // 13 b_nmpn, 14 W_empn, 15 b_empn, 16 W_fc, 17 b_fc
    const float* node_feat = (const float*)d_in[0];
    const float* edge_feat = (const float*)d_in[1];
    const float* W_ih_n    = (const float*)d_in[4];
    const float* b_ih_n    = (const float*)d_in[6];
    const float* b_hh_n    = (const float*)d_in[7];
    const float* W_ih_e    = (const float*)d_in[8];
    const float* b_ih_e    = (const float*)d_in[10];
    const float* b_hh_e    = (const float*)d_in[11];
    const float* W_nmpn    = (const float*)d_in[12];
    const float* b_nmpn    = (const float*)d_in[13];
    const float* W_fc      = (const float*)d_in[16];
    const float* b_fc      = (const float*)d_in[17];
    float* out = (float*)d_out;
    unsigned* wtab = (unsigned*)d_ws;   // needs (128*68+25)*4 = 34916 B

    const int N = in_sizes[0] / NIN;

    pack_weights<<<1, 256, 0, stream>>>(W_ih_n, b_ih_n, b_hh_n,
                                        W_ih_e, b_ih_e, b_hh_e,
                                        W_nmpn, b_nmpn, W_fc, b_fc, wtab);

    const int block = 256;
    const int grid = (N + block - 1) / block;   // 782
    fused_gnn_kernel<<<grid, block, 0, stream>>>(node_feat, edge_feat, wtab, out, N);
}

// Round 12
// 155.527 us; speedup vs baseline: 1.2241x; 1.2241x over previous
//
#include <hip/hip_runtime.h>

#define HID 128
#define NIN 21
#define EIN 2
#define NCLS 4

// ---------------- LDS row layout: one row per d-PAIR m (d0=2m, d1=2m+1) ----
// Units u32 words, stride 100 (400 B). 64 rows = 25600 B.
//  [0..10]   gi pairs d0 (f16x2, scaled L2E)     [33..43] gi pairs d1
//  [11..21]  gg pairs d0 (scaled 2*L2E)          [44..54] gg pairs d1
//  [22..32]  go pairs d0 (scaled L2E)            [55..65] go pairs d1
//  [66..68]  f32 biases d0: bi,bg,bo (scaled)    [69..71] f32 biases d1
//  [72..92]  nmpn hn-pairs k=0..20: (L2E*W2[k][d0], L2E*W2[k][d1]), W2=W_nmpn[:,128+d]
//  [93..96]  fc pairs c=0..3: (Wfc[c][d0], Wfc[c][d1])
//  [97..99]  pad
// All reads wave-uniform broadcasts. The he-half of nmpn (W_nmpn[:,0:128]) and
// b_nmpn live in the G-table (edge-LSTM contribution tabulated over xe).
#define WSTRIDE 100

// G-table: acc_e[k](xe0,xe1) on a 64x64 grid over [-6,6]^2, k padded to 24.
#define GGRID 64
#define GPAD  24
#define GMIN  (-6.0f)
#define GSCALE (63.0f / 12.0f)
#define GSTEP  (12.0f / 63.0f)

#define L2E   1.4426950408889634f   // log2(e)
#define L2E2  2.8853900817779268f   // 2*log2(e)

typedef _Float16 h2_t __attribute__((ext_vector_type(2)));

__device__ __forceinline__ unsigned pack_f16(float a, float b) {
    h2_t h;
    h.x = (_Float16)a;
    h.y = (_Float16)b;
    return __builtin_bit_cast(unsigned, h);
}

__device__ __forceinline__ float fdot2_(unsigned a, unsigned b, float c) {
#if __has_builtin(__builtin_amdgcn_fdot2)
    return __builtin_amdgcn_fdot2(__builtin_bit_cast(h2_t, a),
                                  __builtin_bit_cast(h2_t, b), c, false);
#else
    h2_t ha = __builtin_bit_cast(h2_t, a), hb = __builtin_bit_cast(h2_t, b);
    return fmaf((float)ha.x, (float)hb.x, fmaf((float)ha.y, (float)hb.y, c));
#endif
}

__device__ __forceinline__ float rcp_(float x)  { return __builtin_amdgcn_rcpf(x); }
__device__ __forceinline__ float exp2_(float x) { return __builtin_amdgcn_exp2f(x); }
__device__ __forceinline__ float sigmoid_pre(float gp) { return rcp_(1.0f + exp2_(-gp)); }
__device__ __forceinline__ float sigf(float x)  { return rcp_(1.0f + exp2_(-L2E * x)); }
__device__ __forceinline__ float tanhf_(float x){ return fmaf(2.0f, rcp_(1.0f + exp2_(-L2E2 * x)), -1.0f); }

// Shared-denominator LSTM cell output (gi scaled L2E, gg scaled 2L2E, go scaled L2E):
// cn = sigmoid*tanh, hn = sigmoid(go)*tanh(cn). 6 trans instead of 8.
__device__ __forceinline__ float lstm_h(float gi, float gg, float go) {
    const float u = exp2_(-gi);
    const float v = exp2_(-gg);
    const float cn = (1.0f - v) * rcp_((1.0f + u) * (1.0f + v));
    const float w = exp2_(-go);
    const float t = exp2_(-L2E2 * cn);
    return (1.0f - t) * rcp_((1.0f + w) * (1.0f + t));
}

// ---------------- kernel 1: build the edge-contribution table ----------------
// One wave per grid point; lane l handles d = l and d = l+64. Butterfly-reduce.
__global__ __launch_bounds__(256)
void build_gtab(const float* __restrict__ W_ih_e,
                const float* __restrict__ b_ih_e,
                const float* __restrict__ b_hh_e,
                const float* __restrict__ W_nmpn,
                const float* __restrict__ b_nmpn,
                float* __restrict__ tab)
{
    const int lane = threadIdx.x & 63;
    const int p = blockIdx.x * 4 + (threadIdx.x >> 6);   // 0..4095
    const int iy = p >> 6, ix = p & 63;
    const float x0 = GMIN + (float)ix * GSTEP;
    const float x1 = GMIN + (float)iy * GSTEP;

    float he[2];
#pragma unroll
    for (int h = 0; h < 2; ++h) {
        const int d = lane + 64 * h;
        const float ei = x0 * W_ih_e[(0 * HID + d) * EIN + 0]
                       + x1 * W_ih_e[(0 * HID + d) * EIN + 1]
                       + b_ih_e[0 * HID + d] + b_hh_e[0 * HID + d];
        const float eg = x0 * W_ih_e[(2 * HID + d) * EIN + 0]
                       + x1 * W_ih_e[(2 * HID + d) * EIN + 1]
                       + b_ih_e[2 * HID + d] + b_hh_e[2 * HID + d];
        const float eo = x0 * W_ih_e[(3 * HID + d) * EIN + 0]
                       + x1 * W_ih_e[(3 * HID + d) * EIN + 1]
                       + b_ih_e[3 * HID + d] + b_hh_e[3 * HID + d];
        const float ce = sigf(ei) * tanhf_(eg);
        he[h] = sigf(eo) * tanhf_(ce);
    }

#pragma unroll
    for (int k = 0; k < NIN; ++k) {
        float s = he[0] * (L2E * W_nmpn[k * 2 * HID + lane])
                + he[1] * (L2E * W_nmpn[k * 2 * HID + 64 + lane]);
        s += __shfl_xor(s, 1);
        s += __shfl_xor(s, 2);
        s += __shfl_xor(s, 4);
        s += __shfl_xor(s, 8);
        s += __shfl_xor(s, 16);
        s += __shfl_xor(s, 32);
        if (lane == 0) tab[p * GPAD + k] = s + L2E * b_nmpn[k];
    }
    if (lane == 0) {
        tab[p * GPAD + 21] = 0.0f;
        tab[p * GPAD + 22] = 0.0f;
        tab[p * GPAD + 23] = 0.0f;
    }
}

// ---------------- kernel 2: fused GNN ----------------
__global__ __launch_bounds__(256, 2)
void fused_gnn_kernel(const float* __restrict__ node_feat,  // N*21
                      const float* __restrict__ edge_feat,  // N*2
                      const float* __restrict__ W_ih_n,     // 512*21
                      const float* __restrict__ b_ih_n,     // 512
                      const float* __restrict__ b_hh_n,     // 512
                      const float* __restrict__ W_nmpn,     // 21*256
                      const float* __restrict__ W_fc,       // 4*128
                      const float* __restrict__ b_fc,       // 4
                      const float* __restrict__ tab,        // G-table in d_ws
                      float* __restrict__ out,              // N*4
                      int N)
{
    __shared__ unsigned ldsu[64 * WSTRIDE];   // 25600 B

    const int tid = threadIdx.x;

    // ---- stage weight rows (threads 0..63, one d-pair each) ----
    if (tid < 64) {
        const int m = tid, d0 = 2 * m, d1 = 2 * m + 1;
        unsigned* row = &ldsu[m * WSTRIDE];
        // node gates: (base, scale, word offset) = i:(0,L2E,0) g:(2H,2L2E,11) o:(3H,L2E,22)
#pragma unroll
        for (int g = 0; g < 3; ++g) {
            const int gbase = (g == 0) ? 0 : (g == 1) ? 2 * HID : 3 * HID;
            const float s = (g == 1) ? L2E2 : L2E;
            const int off = 11 * g;
            const float* w0 = &W_ih_n[(gbase + d0) * NIN];
            const float* w1 = &W_ih_n[(gbase + d1) * NIN];
#pragma unroll
            for (int j = 0; j < 10; ++j) {
                row[off + j]      = pack_f16(s * w0[2 * j], s * w0[2 * j + 1]);
                row[33 + off + j] = pack_f16(s * w1[2 * j], s * w1[2 * j + 1]);
            }
            row[off + 10]      = pack_f16(s * w0[20], 0.0f);
            row[33 + off + 10] = pack_f16(s * w1[20], 0.0f);
            row[66 + g] = __float_as_uint(s * (b_ih_n[gbase + d0] + b_hh_n[gbase + d0]));
            row[69 + g] = __float_as_uint(s * (b_ih_n[gbase + d1] + b_hh_n[gbase + d1]));
        }
#pragma unroll
        for (int k = 0; k < NIN; ++k) {
            row[72 + k] = pack_f16(L2E * W_nmpn[k * 2 * HID + HID + d0],
                                   L2E * W_nmpn[k * 2 * HID + HID + d1]);
        }
#pragma unroll
        for (int c = 0; c < NCLS; ++c) {
            row[93 + c] = pack_f16(W_fc[c * HID + d0], W_fc[c * HID + d1]);
        }
    }
    __syncthreads();

    // ---- per-node inputs ----
    const int n = blockIdx.x * blockDim.x + tid;
    const int nidx = (n < N) ? n : (N - 1);

    unsigned xnp[11];
#pragma unroll
    for (int j = 0; j < 10; ++j)
        xnp[j] = pack_f16(node_feat[nidx * NIN + 2 * j], node_feat[nidx * NIN + 2 * j + 1]);
    xnp[10] = pack_f16(node_feat[nidx * NIN + 20], 0.0f);

    // ---- edge contribution via bilinear interpolation of the G-table ----
    float acc[NIN];   // L2E * xn1 pre-activation (bias + edge part from table)
    {
        const float xe0 = edge_feat[nidx * EIN + 0];
        const float xe1 = edge_feat[nidx * EIN + 1];
        const float xi = fminf(fmaxf((xe0 - GMIN) * GSCALE, 0.0f), 62.999f);
        const float yi = fminf(fmaxf((xe1 - GMIN) * GSCALE, 0.0f), 62.999f);
        const int ix = (int)xi, iy = (int)yi;
        const float fx = xi - (float)ix, fy = yi - (float)iy;
        const float w00 = (1.0f - fx) * (1.0f - fy);
        const float w01 = fx * (1.0f - fy);
        const float w10 = (1.0f - fx) * fy;
        const float w11 = fx * fy;
        const float* t00 = tab + (iy * GGRID + ix) * GPAD;
        const float* t01 = t00 + GPAD;
        const float* t10 = t00 + GGRID * GPAD;
        const float* t11 = t10 + GPAD;
#pragma unroll
        for (int q = 0; q < 5; ++q) {
            const float4 a = *reinterpret_cast<const float4*>(t00 + 4 * q);
            const float4 b = *reinterpret_cast<const float4*>(t01 + 4 * q);
            const float4 c = *reinterpret_cast<const float4*>(t10 + 4 * q);
            const float4 e = *reinterpret_cast<const float4*>(t11 + 4 * q);
            acc[4 * q + 0] = w00 * a.x + w01 * b.x + w10 * c.x + w11 * e.x;
            acc[4 * q + 1] = w00 * a.y + w01 * b.y + w10 * c.y + w11 * e.y;
            acc[4 * q + 2] = w00 * a.z + w01 * b.z + w10 * c.z + w11 * e.z;
            acc[4 * q + 3] = w00 * a.w + w01 * b.w + w10 * c.w + w11 * e.w;
        }
        acc[20] = w00 * t00[20] + w01 * t01[20] + w10 * t10[20] + w11 * t11[20];
    }

    float lg[NCLS];
#pragma unroll
    for (int k = 0; k < NCLS; ++k) lg[k] = b_fc[k];

    // ================= iteration 1 (64 d-pairs) =================
    for (int m = 0; m < 64; ++m) {
        const unsigned* row = &ldsu[m * WSTRIDE];

        float gi0 = __uint_as_float(row[66]);
        float gg0 = __uint_as_float(row[67]);
        float go0 = __uint_as_float(row[68]);
        float gi1 = __uint_as_float(row[69]);
        float gg1 = __uint_as_float(row[70]);
        float go1 = __uint_as_float(row[71]);
#pragma unroll
        for (int j = 0; j < 11; ++j) {
            gi0 = fdot2_(xnp[j], row[j],      gi0);
            gg0 = fdot2_(xnp[j], row[11 + j], gg0);
            go0 = fdot2_(xnp[j], row[22 + j], go0);
            gi1 = fdot2_(xnp[j], row[33 + j], gi1);
            gg1 = fdot2_(xnp[j], row[44 + j], gg1);
            go1 = fdot2_(xnp[j], row[55 + j], go1);
        }
        const float hn0 = lstm_h(gi0, gg0, go0);
        const float hn1 = lstm_h(gi1, gg1, go1);

        const unsigned hp = pack_f16(hn0, hn1);
#pragma unroll
        for (int k = 0; k < NIN; ++k) acc[k] = fdot2_(hp, row[72 + k], acc[k]);
    }

    // xn1 = sigmoid(pre) -> repack
#pragma unroll
    for (int j = 0; j < 10; ++j)
        xnp[j] = pack_f16(sigmoid_pre(acc[2 * j]), sigmoid_pre(acc[2 * j + 1]));
    xnp[10] = pack_f16(sigmoid_pre(acc[20]), 0.0f);

    // ================= iteration 2 =================
    for (int m = 0; m < 64; ++m) {
        const unsigned* row = &ldsu[m * WSTRIDE];

        float gi0 = __uint_as_float(row[66]);
        float gg0 = __uint_as_float(row[67]);
        float go0 = __uint_as_float(row[68]);
        float gi1 = __uint_as_float(row[69]);
        float gg1 = __uint_as_float(row[70]);
        float go1 = __uint_as_float(row[71]);
#pragma unroll
        for (int j = 0; j < 11; ++j) {
            gi0 = fdot2_(xnp[j], row[j],      gi0);
            gg0 = fdot2_(xnp[j], row[11 + j], gg0);
            go0 = fdot2_(xnp[j], row[22 + j], go0);
            gi1 = fdot2_(xnp[j], row[33 + j], gi1);
            gg1 = fdot2_(xnp[j], row[44 + j], gg1);
            go1 = fdot2_(xnp[j], row[55 + j], go1);
        }
        const float hn0 = lstm_h(gi0, gg0, go0);
        const float hn1 = lstm_h(gi1, gg1, go1);

        const unsigned hp = pack_f16(hn0, hn1);
        lg[0] = fdot2_(hp, row[93], lg[0]);
        lg[1] = fdot2_(hp, row[94], lg[1]);
        lg[2] = fdot2_(hp, row[95], lg[2]);
        lg[3] = fdot2_(hp, row[96], lg[3]);
    }

    // ================= log_softmax + store =================
    const float mx = fmaxf(fmaxf(lg[0], lg[1]), fmaxf(lg[2], lg[3]));
    float s = 0.0f;
#pragma unroll
    for (int k = 0; k < NCLS; ++k) s += exp2_(L2E * (lg[k] - mx));
    const float lse = __logf(s) + mx;

    if (n < N) {
        float4 o4;
        o4.x = lg[0] - lse;
        o4.y = lg[1] - lse;
        o4.z = lg[2] - lse;
        o4.w = lg[3] - lse;
        *reinterpret_cast<float4*>(&out[n * NCLS]) = o4;
    }
}

extern "C" void kernel_launch(void* const* d_in, const int* in_sizes, int n_in,
                              void* d_out, int out_size, void* d_ws, size_t ws_size,
                              hipStream_t stream)
{
    // setup_inputs order:
    // 0 node_feat, 1 edge_feat, 2 src, 3 dst, 4 W_ih_n, 5 W_hh_n, 6 b_ih_n,
    // 7 b_hh_n, 8 W_ih_e, 9 W_hh_e, 10 b_ih_e, 11 b_hh_e, 12 W_nmpn,
    // 13 b_nmpn, 14 W_empn, 15 b_empn, 16 W_fc, 17 b_fc
    const float* node_feat = (const float*)d_in[0];
    const float* edge_feat = (const float*)d_in[1];
    const float* W_ih_n    = (const float*)d_in[4];
    const float* b_ih_n    = (const float*)d_in[6];
    const float* b_hh_n    = (const float*)d_in[7];
    const float* W_ih_e    = (const float*)d_in[8];
    const float* b_ih_e    = (const float*)d_in[10];
    const float* b_hh_e    = (const float*)d_in[11];
    const float* W_nmpn    = (const float*)d_in[12];
    const float* b_nmpn    = (const float*)d_in[13];
    const float* W_fc      = (const float*)d_in[16];
    const float* b_fc      = (const float*)d_in[17];
    float* out = (float*)d_out;
    float* tab = (float*)d_ws;   // 64*64*24*4 = 393216 B

    const int N = in_sizes[0] / NIN;

    build_gtab<<<1024, 256, 0, stream>>>(W_ih_e, b_ih_e, b_hh_e, W_nmpn, b_nmpn, tab);

    const int block = 256;
    const int grid = (N + block - 1) / block;   // 782
    fused_gnn_kernel<<<grid, block, 0, stream>>>(node_feat, edge_feat,
                                                 W_ih_n, b_ih_n, b_hh_n,
                                                 W_nmpn, W_fc, b_fc, tab, out, N);
}

// Round 13
// 145.016 us; speedup vs baseline: 1.3128x; 1.0725x over previous
//
#include <hip/hip_runtime.h>

#define HID 128
#define NIN 21
#define EIN 2
#define NCLS 4

// ---------------- LDS row layout: one row per d-PAIR m (d0=2m, d1=2m+1) ----
// Units u32 words, stride 100 (400 B). 64 rows = 25600 B.
//  [0..10]   gi pairs d0 (f16x2, scaled L2E)     [33..43] gi pairs d1
//  [11..21]  gg pairs d0 (scaled 2*L2E)          [44..54] gg pairs d1
//  [22..32]  go pairs d0 (scaled L2E)            [55..65] go pairs d1
//  [66..68]  f32 biases d0: bi,bg,bo (scaled)    [69..71] f32 biases d1
//  [72..92]  nmpn hn-pairs k=0..20: (L2E*W2[k][d0], L2E*W2[k][d1])
//  [93..96]  fc pairs c=0..3
//  [97..99]  pad
// NPT=2 (r13): both of a thread's nodes consume each broadcast word -> LDS
// cycles per node HALVED. r12 PMC arithmetic: 3125 waves x 2752 ds_read_b128
// x 12cyc / 256 CU = 403k cyc/CU = 168us = the wall. This cuts it to ~84us,
// rebalancing against ~85us of VALU issue.
#define WSTRIDE 100

// G-table: edge-LSTM contribution acc_e[k](xe0,xe1), 64x64 grid over [-6,6]^2.
#define GGRID 64
#define GPAD  24
#define GMIN  (-6.0f)
#define GSCALE (63.0f / 12.0f)
#define GSTEP  (12.0f / 63.0f)

#define L2E   1.4426950408889634f   // log2(e)
#define L2E2  2.8853900817779268f   // 2*log2(e)

typedef _Float16 h2_t __attribute__((ext_vector_type(2)));

__device__ __forceinline__ unsigned pack_f16(float a, float b) {
    h2_t h;
    h.x = (_Float16)a;
    h.y = (_Float16)b;
    return __builtin_bit_cast(unsigned, h);
}

__device__ __forceinline__ float fdot2_(unsigned a, unsigned b, float c) {
#if __has_builtin(__builtin_amdgcn_fdot2)
    return __builtin_amdgcn_fdot2(__builtin_bit_cast(h2_t, a),
                                  __builtin_bit_cast(h2_t, b), c, false);
#else
    h2_t ha = __builtin_bit_cast(h2_t, a), hb = __builtin_bit_cast(h2_t, b);
    return fmaf((float)ha.x, (float)hb.x, fmaf((float)ha.y, (float)hb.y, c));
#endif
}

__device__ __forceinline__ float rcp_(float x)  { return __builtin_amdgcn_rcpf(x); }
__device__ __forceinline__ float exp2_(float x) { return __builtin_amdgcn_exp2f(x); }
__device__ __forceinline__ float sigmoid_pre(float gp) { return rcp_(1.0f + exp2_(-gp)); }
__device__ __forceinline__ float sigf(float x)  { return rcp_(1.0f + exp2_(-L2E * x)); }
__device__ __forceinline__ float tanhf_(float x){ return fmaf(2.0f, rcp_(1.0f + exp2_(-L2E2 * x)), -1.0f); }

// Shared-denominator LSTM h (6 trans instead of 8); gi/go scaled L2E, gg 2*L2E.
__device__ __forceinline__ float lstm_h(float gi, float gg, float go) {
    const float u = exp2_(-gi);
    const float v = exp2_(-gg);
    const float cn = (1.0f - v) * rcp_((1.0f + u) * (1.0f + v));
    const float w = exp2_(-go);
    const float t = exp2_(-L2E2 * cn);
    return (1.0f - t) * rcp_((1.0f + w) * (1.0f + t));
}

// ---------------- kernel 1: build the edge-contribution table ----------------
__global__ __launch_bounds__(256)
void build_gtab(const float* __restrict__ W_ih_e,
                const float* __restrict__ b_ih_e,
                const float* __restrict__ b_hh_e,
                const float* __restrict__ W_nmpn,
                const float* __restrict__ b_nmpn,
                float* __restrict__ tab)
{
    const int lane = threadIdx.x & 63;
    const int p = blockIdx.x * 4 + (threadIdx.x >> 6);   // 0..4095
    const int iy = p >> 6, ix = p & 63;
    const float x0 = GMIN + (float)ix * GSTEP;
    const float x1 = GMIN + (float)iy * GSTEP;

    float he[2];
#pragma unroll
    for (int h = 0; h < 2; ++h) {
        const int d = lane + 64 * h;
        const float ei = x0 * W_ih_e[(0 * HID + d) * EIN + 0]
                       + x1 * W_ih_e[(0 * HID + d) * EIN + 1]
                       + b_ih_e[0 * HID + d] + b_hh_e[0 * HID + d];
        const float eg = x0 * W_ih_e[(2 * HID + d) * EIN + 0]
                       + x1 * W_ih_e[(2 * HID + d) * EIN + 1]
                       + b_ih_e[2 * HID + d] + b_hh_e[2 * HID + d];
        const float eo = x0 * W_ih_e[(3 * HID + d) * EIN + 0]
                       + x1 * W_ih_e[(3 * HID + d) * EIN + 1]
                       + b_ih_e[3 * HID + d] + b_hh_e[3 * HID + d];
        const float ce = sigf(ei) * tanhf_(eg);
        he[h] = sigf(eo) * tanhf_(ce);
    }

#pragma unroll
    for (int k = 0; k < NIN; ++k) {
        float s = he[0] * (L2E * W_nmpn[k * 2 * HID + lane])
                + he[1] * (L2E * W_nmpn[k * 2 * HID + 64 + lane]);
        s += __shfl_xor(s, 1);
        s += __shfl_xor(s, 2);
        s += __shfl_xor(s, 4);
        s += __shfl_xor(s, 8);
        s += __shfl_xor(s, 16);
        s += __shfl_xor(s, 32);
        if (lane == 0) tab[p * GPAD + k] = s + L2E * b_nmpn[k];
    }
    if (lane == 0) {
        tab[p * GPAD + 21] = 0.0f;
        tab[p * GPAD + 22] = 0.0f;
        tab[p * GPAD + 23] = 0.0f;
    }
}

// ---------------- kernel 2: fused GNN, 2 nodes/thread ----------------
__global__ __launch_bounds__(128, 2)
void fused_gnn_kernel(const float* __restrict__ node_feat,  // N*21
                      const float* __restrict__ edge_feat,  // N*2
                      const float* __restrict__ W_ih_n,     // 512*21
                      const float* __restrict__ b_ih_n,     // 512
                      const float* __restrict__ b_hh_n,     // 512
                      const float* __restrict__ W_nmpn,     // 21*256
                      const float* __restrict__ W_fc,       // 4*128
                      const float* __restrict__ b_fc,       // 4
                      const float* __restrict__ tab,        // G-table in d_ws
                      float* __restrict__ out,              // N*4
                      int N)
{
    __shared__ unsigned ldsu[64 * WSTRIDE];   // 25600 B

    const int tid = threadIdx.x;

    // ---- stage weight rows (threads 0..63, one d-pair each) ----
    if (tid < 64) {
        const int m = tid, d0 = 2 * m, d1 = 2 * m + 1;
        unsigned* row = &ldsu[m * WSTRIDE];
#pragma unroll
        for (int g = 0; g < 3; ++g) {
            const int gbase = (g == 0) ? 0 : (g == 1) ? 2 * HID : 3 * HID;
            const float s = (g == 1) ? L2E2 : L2E;
            const int off = 11 * g;
            const float* w0 = &W_ih_n[(gbase + d0) * NIN];
            const float* w1 = &W_ih_n[(gbase + d1) * NIN];
#pragma unroll
            for (int j = 0; j < 10; ++j) {
                row[off + j]      = pack_f16(s * w0[2 * j], s * w0[2 * j + 1]);
                row[33 + off + j] = pack_f16(s * w1[2 * j], s * w1[2 * j + 1]);
            }
            row[off + 10]      = pack_f16(s * w0[20], 0.0f);
            row[33 + off + 10] = pack_f16(s * w1[20], 0.0f);
            row[66 + g] = __float_as_uint(s * (b_ih_n[gbase + d0] + b_hh_n[gbase + d0]));
            row[69 + g] = __float_as_uint(s * (b_ih_n[gbase + d1] + b_hh_n[gbase + d1]));
        }
#pragma unroll
        for (int k = 0; k < NIN; ++k) {
            row[72 + k] = pack_f16(L2E * W_nmpn[k * 2 * HID + HID + d0],
                                   L2E * W_nmpn[k * 2 * HID + HID + d1]);
        }
#pragma unroll
        for (int c = 0; c < NCLS; ++c) {
            row[93 + c] = pack_f16(W_fc[c * HID + d0], W_fc[c * HID + d1]);
        }
    }
    __syncthreads();

    // ---- node assignment: 2 nodes per thread ----
    const int base = blockIdx.x * 256;
    const int n0 = base + tid;
    const int n1 = base + tid + 128;
    const int i0 = (n0 < N) ? n0 : (N - 1);
    const int i1 = (n1 < N) ? n1 : (N - 1);

    unsigned x0[11], x1[11];
#pragma unroll
    for (int j = 0; j < 10; ++j) {
        x0[j] = pack_f16(node_feat[i0 * NIN + 2 * j], node_feat[i0 * NIN + 2 * j + 1]);
        x1[j] = pack_f16(node_feat[i1 * NIN + 2 * j], node_feat[i1 * NIN + 2 * j + 1]);
    }
    x0[10] = pack_f16(node_feat[i0 * NIN + 20], 0.0f);
    x1[10] = pack_f16(node_feat[i1 * NIN + 20], 0.0f);

    // ---- edge contribution via bilinear interp of the G-table (per node) ----
    float a0[NIN], a1[NIN];
#pragma unroll
    for (int w = 0; w < 2; ++w) {
        const int ii = w ? i1 : i0;
        float* accp = w ? a1 : a0;
        const float xe0 = edge_feat[ii * EIN + 0];
        const float xe1 = edge_feat[ii * EIN + 1];
        const float xi = fminf(fmaxf((xe0 - GMIN) * GSCALE, 0.0f), 62.999f);
        const float yi = fminf(fmaxf((xe1 - GMIN) * GSCALE, 0.0f), 62.999f);
        const int ix = (int)xi, iy = (int)yi;
        const float fx = xi - (float)ix, fy = yi - (float)iy;
        const float w00 = (1.0f - fx) * (1.0f - fy);
        const float w01 = fx * (1.0f - fy);
        const float w10 = (1.0f - fx) * fy;
        const float w11 = fx * fy;
        const float* t00 = tab + (iy * GGRID + ix) * GPAD;
        const float* t01 = t00 + GPAD;
        const float* t10 = t00 + GGRID * GPAD;
        const float* t11 = t10 + GPAD;
#pragma unroll
        for (int q = 0; q < 5; ++q) {
            const float4 a = *reinterpret_cast<const float4*>(t00 + 4 * q);
            const float4 b = *reinterpret_cast<const float4*>(t01 + 4 * q);
            const float4 c = *reinterpret_cast<const float4*>(t10 + 4 * q);
            const float4 e = *reinterpret_cast<const float4*>(t11 + 4 * q);
            accp[4 * q + 0] = w00 * a.x + w01 * b.x + w10 * c.x + w11 * e.x;
            accp[4 * q + 1] = w00 * a.y + w01 * b.y + w10 * c.y + w11 * e.y;
            accp[4 * q + 2] = w00 * a.z + w01 * b.z + w10 * c.z + w11 * e.z;
            accp[4 * q + 3] = w00 * a.w + w01 * b.w + w10 * c.w + w11 * e.w;
        }
        accp[20] = w00 * t00[20] + w01 * t01[20] + w10 * t10[20] + w11 * t11[20];
    }

    float l0[NCLS], l1[NCLS];
#pragma unroll
    for (int k = 0; k < NCLS; ++k) { l0[k] = b_fc[k]; l1[k] = l0[k]; }

    // ================= iteration 1 (64 d-pairs) =================
    for (int m = 0; m < 64; ++m) {
        const unsigned* row = &ldsu[m * WSTRIDE];

        float gi00 = __uint_as_float(row[66]), gi01 = gi00;
        float gg00 = __uint_as_float(row[67]), gg01 = gg00;
        float go00 = __uint_as_float(row[68]), go01 = go00;
        float gi10 = __uint_as_float(row[69]), gi11 = gi10;
        float gg10 = __uint_as_float(row[70]), gg11 = gg10;
        float go10 = __uint_as_float(row[71]), go11 = go10;
#pragma unroll
        for (int j = 0; j < 11; ++j) {
            const unsigned wi0 = row[j],      wg0 = row[11 + j], wo0 = row[22 + j];
            const unsigned wi1 = row[33 + j], wg1 = row[44 + j], wo1 = row[55 + j];
            gi00 = fdot2_(x0[j], wi0, gi00);  gi01 = fdot2_(x1[j], wi0, gi01);
            gg00 = fdot2_(x0[j], wg0, gg00);  gg01 = fdot2_(x1[j], wg0, gg01);
            go00 = fdot2_(x0[j], wo0, go00);  go01 = fdot2_(x1[j], wo0, go01);
            gi10 = fdot2_(x0[j], wi1, gi10);  gi11 = fdot2_(x1[j], wi1, gi11);
            gg10 = fdot2_(x0[j], wg1, gg10);  gg11 = fdot2_(x1[j], wg1, gg11);
            go10 = fdot2_(x0[j], wo1, go10);  go11 = fdot2_(x1[j], wo1, go11);
        }
        // node0: d0,d1 ; node1: d0,d1
        const unsigned hp0 = pack_f16(lstm_h(gi00, gg00, go00), lstm_h(gi10, gg10, go10));
        const unsigned hp1 = pack_f16(lstm_h(gi01, gg01, go01), lstm_h(gi11, gg11, go11));
#pragma unroll
        for (int k = 0; k < NIN; ++k) {
            const unsigned wm = row[72 + k];
            a0[k] = fdot2_(hp0, wm, a0[k]);
            a1[k] = fdot2_(hp1, wm, a1[k]);
        }
    }

    // xn1 = sigmoid(pre) -> repack
#pragma unroll
    for (int j = 0; j < 10; ++j) {
        x0[j] = pack_f16(sigmoid_pre(a0[2 * j]), sigmoid_pre(a0[2 * j + 1]));
        x1[j] = pack_f16(sigmoid_pre(a1[2 * j]), sigmoid_pre(a1[2 * j + 1]));
    }
    x0[10] = pack_f16(sigmoid_pre(a0[20]), 0.0f);
    x1[10] = pack_f16(sigmoid_pre(a1[20]), 0.0f);

    // ================= iteration 2 =================
    for (int m = 0; m < 64; ++m) {
        const unsigned* row = &ldsu[m * WSTRIDE];

        float gi00 = __uint_as_float(row[66]), gi01 = gi00;
        float gg00 = __uint_as_float(row[67]), gg01 = gg00;
        float go00 = __uint_as_float(row[68]), go01 = go00;
        float gi10 = __uint_as_float(row[69]), gi11 = gi10;
        float gg10 = __uint_as_float(row[70]), gg11 = gg10;
        float go10 = __uint_as_float(row[71]), go11 = go10;
#pragma unroll
        for (int j = 0; j < 11; ++j) {
            const unsigned wi0 = row[j],      wg0 = row[11 + j], wo0 = row[22 + j];
            const unsigned wi1 = row[33 + j], wg1 = row[44 + j], wo1 = row[55 + j];
            gi00 = fdot2_(x0[j], wi0, gi00);  gi01 = fdot2_(x1[j], wi0, gi01);
            gg00 = fdot2_(x0[j], wg0, gg00);  gg01 = fdot2_(x1[j], wg0, gg01);
            go00 = fdot2_(x0[j], wo0, go00);  go01 = fdot2_(x1[j], wo0, go01);
            gi10 = fdot2_(x0[j], wi1, gi10);  gi11 = fdot2_(x1[j], wi1, gi11);
            gg10 = fdot2_(x0[j], wg1, gg10);  gg11 = fdot2_(x1[j], wg1, gg11);
            go10 = fdot2_(x0[j], wo1, go10);  go11 = fdot2_(x1[j], wo1, go11);
        }
        const unsigned hp0 = pack_f16(lstm_h(gi00, gg00, go00), lstm_h(gi10, gg10, go10));
        const unsigned hp1 = pack_f16(lstm_h(gi01, gg01, go01), lstm_h(gi11, gg11, go11));
        l0[0] = fdot2_(hp0, row[93], l0[0]);  l1[0] = fdot2_(hp1, row[93], l1[0]);
        l0[1] = fdot2_(hp0, row[94], l0[1]);  l1[1] = fdot2_(hp1, row[94], l1[1]);
        l0[2] = fdot2_(hp0, row[95], l0[2]);  l1[2] = fdot2_(hp1, row[95], l1[2]);
        l0[3] = fdot2_(hp0, row[96], l0[3]);  l1[3] = fdot2_(hp1, row[96], l1[3]);
    }

    // ================= log_softmax + store (per node) =================
    {
        const float mx = fmaxf(fmaxf(l0[0], l0[1]), fmaxf(l0[2], l0[3]));
        float s = 0.0f;
#pragma unroll
        for (int k = 0; k < NCLS; ++k) s += exp2_(L2E * (l0[k] - mx));
        const float lse = __logf(s) + mx;
        if (n0 < N) {
            float4 o4;
            o4.x = l0[0] - lse; o4.y = l0[1] - lse;
            o4.z = l0[2] - lse; o4.w = l0[3] - lse;
            *reinterpret_cast<float4*>(&out[n0 * NCLS]) = o4;
        }
    }
    {
        const float mx = fmaxf(fmaxf(l1[0], l1[1]), fmaxf(l1[2], l1[3]));
        float s = 0.0f;
#pragma unroll
        for (int k = 0; k < NCLS; ++k) s += exp2_(L2E * (l1[k] - mx));
        const float lse = __logf(s) + mx;
        if (n1 < N) {
            float4 o4;
            o4.x = l1[0] - lse; o4.y = l1[1] - lse;
            o4.z = l1[2] - lse; o4.w = l1[3] - lse;
            *reinterpret_cast<float4*>(&out[n1 * NCLS]) = o4;
        }
    }
}

extern "C" void kernel_launch(void* const* d_in, const int* in_sizes, int n_in,
                              void* d_out, int out_size, void* d_ws, size_t ws_size,
                              hipStream_t stream)
{
    // setup_inputs order:
    // 0 node_feat, 1 edge_feat, 2 src, 3 dst, 4 W_ih_n, 5 W_hh_n, 6 b_ih_n,
    // 7 b_hh_n, 8 W_ih_e, 9 W_hh_e, 10 b_ih_e, 11 b_hh_e, 12 W_nmpn,
    // 13 b_nmpn, 14 W_empn, 15 b_empn, 16 W_fc, 17 b_fc
    const float* node_feat = (const float*)d_in[0];
    const float* edge_feat = (const float*)d_in[1];
    const float* W_ih_n    = (const float*)d_in[4];
    const float* b_ih_n    = (const float*)d_in[6];
    const float* b_hh_n    = (const float*)d_in[7];
    const float* W_ih_e    = (const float*)d_in[8];
    const float* b_ih_e    = (const float*)d_in[10];
    const float* b_hh_e    = (const float*)d_in[11];
    const float* W_nmpn    = (const float*)d_in[12];
    const float* b_nmpn    = (const float*)d_in[13];
    const float* W_fc      = (const float*)d_in[16];
    const float* b_fc      = (const float*)d_in[17];
    float* out = (float*)d_out;
    float* tab = (float*)d_ws;   // 64*64*24*4 = 393216 B

    const int N = in_sizes[0] / NIN;

    build_gtab<<<1024, 256, 0, stream>>>(W_ih_e, b_ih_e, b_hh_e, W_nmpn, b_nmpn, tab);

    const int block = 128;                    // 2 waves, 2 nodes/thread
    const int grid = (N + 256 - 1) / 256;     // 782 blocks of 256 nodes
    fused_gnn_kernel<<<grid, block, 0, stream>>>(node_feat, edge_feat,
                                                 W_ih_n, b_ih_n, b_hh_n,
                                                 W_nmpn, W_fc, b_fc, tab, out, N);
}